// Round 5
// baseline (1026.936 us; speedup 1.0000x reference)
//
#include <hip/hip_runtime.h>
#include <cmath>

// ---- problem constants ----
constexpr int Bb  = 512;
constexpr int Cc  = 12;
constexpr int Ww  = 4;
constexpr int Ff  = 512;
constexpr int Nn  = Bb * Ww;        // 2048
constexpr int Gg  = 3 * Ff;         // 1536
constexpr int Mx  = Nn * Cc;        // 24576

typedef __attribute__((ext_vector_type(8))) short bf16x8;
typedef __attribute__((ext_vector_type(4))) float f32x4;

__device__ __forceinline__ float sigm(float v) { return 1.f / (1.f + expf(-v)); }
__device__ __forceinline__ float b2f(ushort u) { union { float f; unsigned i; } v; v.i = ((unsigned)u) << 16; return v.f; }
__device__ __forceinline__ ushort f2b(float f) {
    union { float f; unsigned i; } v; v.f = f;
    unsigned r = v.i + 0x7FFFu + ((v.i >> 16) & 1u);
    return (ushort)(r >> 16);
}
__device__ __forceinline__ void async16(const ushort* g, ushort* l) {
    __builtin_amdgcn_global_load_lds(
        (const __attribute__((address_space(1))) unsigned int*)g,
        (__attribute__((address_space(3))) unsigned int*)l, 16, 0, 0);
}

// =============== generic bf16 MFMA GEMM ===============
// C[M,N] = A[M,K] @ Bt[N,K]^T.  Block 128x128, 4 waves; swapped-operand epilogue
// (lane holds 4 consecutive cols) -> packed 8B/16B stores.
__global__ __launch_bounds__(256) void mfma_gemm(
    const ushort* __restrict__ A, const ushort* __restrict__ Bt,
    float* __restrict__ Cf, ushort* __restrict__ Cb,
    const float* __restrict__ colBias,
    int N, int K, int kLen, int MN, int gridY)
{
    __shared__ ushort As[128 * 64], Bs[128 * 64];
    const int tid = threadIdx.x;
    const int ln = tid & 63, wv = tid >> 6;
    const int l = blockIdx.x;
    const int by = l % gridY, bx = l / gridY, bz = blockIdx.y;
    const int srow = ln >> 3;
    const int kslot = (ln & 7) ^ srow;
    const int rowA0 = by * 128 + wv * 32;
    const int rowB0 = bx * 128 + wv * 32;
    const ushort* ga = A  + (long)(rowA0 + srow) * K + bz * kLen + kslot * 8;
    const ushort* gb = Bt + (long)(rowB0 + srow) * K + bz * kLen + kslot * 8;
    ushort* la = As + wv * 32 * 64;
    ushort* lb = Bs + wv * 32 * 64;
    const int rbase = (wv >> 1) * 64, cbase = (wv & 1) * 64;
    const int mrow = ln & 15, quad = ln >> 4;

    f32x4 acc[4][4] = {};

    for (int kc = 0; kc < kLen; kc += 64) {
        #pragma unroll
        for (int i = 0; i < 4; ++i) {
            async16(ga + (long)(i * 8) * K, la + i * 8 * 64);
            async16(gb + (long)(i * 8) * K, lb + i * 8 * 64);
        }
        ga += 64; gb += 64;
        __syncthreads();
        #pragma unroll
        for (int s = 0; s < 2; ++s) {
            const int sw = (((s << 2) + quad) ^ (ln & 7)) << 3;
            bf16x8 af[4], bf[4];
            #pragma unroll
            for (int i = 0; i < 4; ++i)
                af[i] = *(const bf16x8*)(As + (rbase + i * 16 + mrow) * 64 + sw);
            #pragma unroll
            for (int j = 0; j < 4; ++j)
                bf[j] = *(const bf16x8*)(Bs + (cbase + j * 16 + mrow) * 64 + sw);
            #pragma unroll
            for (int i = 0; i < 4; ++i)
                #pragma unroll
                for (int j = 0; j < 4; ++j)
                    acc[i][j] = __builtin_amdgcn_mfma_f32_16x16x32_bf16(bf[j], af[i], acc[i][j], 0, 0, 0);
        }
        __syncthreads();
    }

    const int gr0 = by * 128 + rbase + mrow;
    const int gc0 = bx * 128 + cbase + quad * 4;
    if (Cb) {
        #pragma unroll
        for (int i = 0; i < 4; ++i) {
            const long rowoff = (long)(gr0 + i * 16) * N;
            #pragma unroll
            for (int j = 0; j < 4; ++j) {
                float c0 = 0.f, c1 = 0.f, c2 = 0.f, c3 = 0.f;
                if (colBias) {
                    const float4 cb4 = *(const float4*)(colBias + gc0 + j * 16);
                    c0 = cb4.x; c1 = cb4.y; c2 = cb4.z; c3 = cb4.w;
                }
                union { ushort u[4]; uint2 v; } pk;
                pk.u[0] = f2b(acc[i][j][0] + c0);
                pk.u[1] = f2b(acc[i][j][1] + c1);
                pk.u[2] = f2b(acc[i][j][2] + c2);
                pk.u[3] = f2b(acc[i][j][3] + c3);
                *(uint2*)&Cb[rowoff + gc0 + j * 16] = pk.v;
            }
        }
    } else {
        float* Co = Cf + (long)bz * MN;
        #pragma unroll
        for (int i = 0; i < 4; ++i) {
            const long rowoff = (long)(gr0 + i * 16) * N;
            #pragma unroll
            for (int j = 0; j < 4; ++j)
                *(f32x4*)&Co[rowoff + gc0 + j * 16] = acc[i][j];
        }
    }
}

// =============== persistent GRU: all 12 steps, one dispatch ===============
// Grid 512, 2 blocks/CU guaranteed (LDS 40KB -> 4/CU cap, VGPR << 256).
// Grid barrier between steps: release-RMW + acquire-spin on cnt[t] (device scope).
// Block swizzle keeps each weight f-slice on one XCD's L2 across all steps.
__global__ __launch_bounds__(256) void gru_all(
    const ushort* __restrict__ xb,
    const ushort* __restrict__ whhB, const ushort* __restrict__ wihB,
    const float* __restrict__ bih, const float* __restrict__ bhh,
    ushort* __restrict__ h0, ushort* __restrict__ h1,
    ushort* __restrict__ G, unsigned* __restrict__ cnt)
{
    __shared__ ushort Ah[64 * 64], Ax[64 * 64], Bh[96 * 64], Bx[96 * 64];
    const int tid = threadIdx.x, ln = tid & 63, wv = tid >> 6;
    const int p = blockIdx.x;
    const int fb = ((p & 7) << 1) | (p >> 8);   // same fb -> same XCD (p%8 fixed)
    const int mb = (p >> 3) & 31;
    const int srow = ln >> 3, kslot = (ln & 7) ^ srow;
    const int mrow = ln & 15, quad = ln >> 4;
    const int n = mb * 64 + wv * 16 + mrow;

    // hoist per-lane bias constants (t-invariant)
    float br[2][4], bz[2][4], bnI[2][4], bnH[2][4];
    #pragma unroll
    for (int ft = 0; ft < 2; ++ft) {
        const int f0 = fb * 32 + ft * 16 + quad * 4;
        const float4 bir = *(const float4*)(bih + f0);
        const float4 biz = *(const float4*)(bih + 512 + f0);
        const float4 bin = *(const float4*)(bih + 1024 + f0);
        const float4 bhr = *(const float4*)(bhh + f0);
        const float4 bhz = *(const float4*)(bhh + 512 + f0);
        const float4 bhn = *(const float4*)(bhh + 1024 + f0);
        br[ft][0] = bir.x + bhr.x; br[ft][1] = bir.y + bhr.y; br[ft][2] = bir.z + bhr.z; br[ft][3] = bir.w + bhr.w;
        bz[ft][0] = biz.x + bhz.x; bz[ft][1] = biz.y + bhz.y; bz[ft][2] = biz.z + bhz.z; bz[ft][3] = biz.w + bhz.w;
        bnI[ft][0] = bin.x; bnI[ft][1] = bin.y; bnI[ft][2] = bin.z; bnI[ft][3] = bin.w;
        bnH[ft][0] = bhn.x; bnH[ft][1] = bhn.y; bnH[ft][2] = bhn.z; bnH[ft][3] = bhn.w;
    }

    const ushort* hp = h0;
    ushort* hq = h1;
    for (int t = 0; t < Cc; ++t) {
        f32x4 aH[6] = {}, aX[6] = {};
        const ushort* hrow = hp + (long)(mb * 64) * 512;

        for (int kc = 0; kc < 512; kc += 64) {
            #pragma unroll
            for (int a = 0; a < 2; ++a) {
                const int r0 = (wv * 2 + a) * 8;
                async16(hrow + (long)(r0 + srow) * 512 + kc + kslot * 8, Ah + r0 * 64);
                async16(xb + ((long)(mb * 64 + r0 + srow) * 12 + t) * 512 + kc + kslot * 8, Ax + r0 * 64);
            }
            #pragma unroll
            for (int b8 = 0; b8 < 3; ++b8) {
                const int lr0 = (wv * 3 + b8) * 8;
                const int lr = lr0 + srow;
                const int g = lr >> 5, fc = lr & 31;
                const long wr = (long)(g * 512 + fb * 32 + fc) * 512 + kc + kslot * 8;
                async16(whhB + wr, Bh + lr0 * 64);
                async16(wihB + wr, Bx + lr0 * 64);
            }
            __syncthreads();
            #pragma unroll
            for (int s = 0; s < 2; ++s) {
                const int sw = (((s << 2) + quad) ^ (ln & 7)) << 3;
                const bf16x8 ah = *(const bf16x8*)(Ah + (wv * 16 + mrow) * 64 + sw);
                const bf16x8 ax = *(const bf16x8*)(Ax + (wv * 16 + mrow) * 64 + sw);
                #pragma unroll
                for (int jt = 0; jt < 6; ++jt) {
                    const bf16x8 bh = *(const bf16x8*)(Bh + (jt * 16 + mrow) * 64 + sw);
                    aH[jt] = __builtin_amdgcn_mfma_f32_16x16x32_bf16(bh, ah, aH[jt], 0, 0, 0);
                }
                #pragma unroll
                for (int jt = 0; jt < 6; ++jt) {
                    const bf16x8 bx2 = *(const bf16x8*)(Bx + (jt * 16 + mrow) * 64 + sw);
                    aX[jt] = __builtin_amdgcn_mfma_f32_16x16x32_bf16(bx2, ax, aX[jt], 0, 0, 0);
                }
            }
            __syncthreads();
        }

        #pragma unroll
        for (int ft = 0; ft < 2; ++ft) {
            const int f0 = fb * 32 + ft * 16 + quad * 4;
            union { ushort u[4]; uint2 v; } hpk;
            hpk.v = *(const uint2*)(hp + (long)n * 512 + f0);
            union { ushort u[4]; uint2 v; } o;
            #pragma unroll
            for (int r = 0; r < 4; ++r) {
                const float rr = sigm(aH[ft][r] + aX[ft][r] + br[ft][r]);
                const float zz = sigm(aH[2 + ft][r] + aX[2 + ft][r] + bz[ft][r]);
                const float nv = tanhf(aX[4 + ft][r] + bnI[ft][r] + rr * (aH[4 + ft][r] + bnH[ft][r]));
                o.u[r] = f2b((1.f - zz) * nv + zz * b2f(hpk.u[r]));
            }
            *(uint2*)&hq[(long)n * 512 + f0] = o.v;
            *(uint2*)&G[(long)(n * 12 + t) * 512 + f0] = o.v;
        }

        if (t < Cc - 1) {
            __syncthreads();                        // drains vmcnt -> stores in L2
            if (tid == 0) {
                __hip_atomic_fetch_add(&cnt[t], 1u, __ATOMIC_RELEASE, __HIP_MEMORY_SCOPE_AGENT);
                while (__hip_atomic_load(&cnt[t], __ATOMIC_ACQUIRE, __HIP_MEMORY_SCOPE_AGENT) < 512u)
                    __builtin_amdgcn_s_sleep(8);
            }
            __syncthreads();
        }
        const ushort* tmp = hp; hp = hq; hq = (ushort*)tmp;
    }
}

// =============== conversions ===============
__global__ __launch_bounds__(256) void cvt_x(const float* __restrict__ x, ushort* __restrict__ xb)
{
    const int idx = blockIdx.x * 256 + threadIdx.x;   // Mx*64
    const int m = idx >> 6, f8 = (idx & 63) << 3;
    const int n = m / 12, c = m - n * 12;
    const int b = n >> 2, w = n & 3;
    const float* src = x + (((b * 12 + c) * 4 + w) << 9) + f8;
    const float4 a = *(const float4*)src, q = *(const float4*)(src + 4);
    uint4 o;
    o.x = (unsigned)f2b(a.x) | ((unsigned)f2b(a.y) << 16);
    o.y = (unsigned)f2b(a.z) | ((unsigned)f2b(a.w) << 16);
    o.z = (unsigned)f2b(q.x) | ((unsigned)f2b(q.y) << 16);
    o.w = (unsigned)f2b(q.z) | ((unsigned)f2b(q.w) << 16);
    *(uint4*)(xb + (m << 9) + f8) = o;
}

__global__ __launch_bounds__(256) void cvt_w2(
    const float* __restrict__ wih, const float* __restrict__ whh,
    ushort* __restrict__ wihB, ushort* __restrict__ whhB)
{
    int bx = blockIdx.x;
    const float* s; ushort* d;
    if (bx < 384) { s = wih; d = wihB; } else { s = whh; d = whhB; bx -= 384; }
    const int e = (bx * 256 + threadIdx.x) << 3;
    const float4 a = *(const float4*)(s + e), q = *(const float4*)(s + e + 4);
    uint4 o;
    o.x = (unsigned)f2b(a.x) | ((unsigned)f2b(a.y) << 16);
    o.y = (unsigned)f2b(a.z) | ((unsigned)f2b(a.w) << 16);
    o.z = (unsigned)f2b(q.x) | ((unsigned)f2b(q.y) << 16);
    o.w = (unsigned)f2b(q.z) | ((unsigned)f2b(q.w) << 16);
    *(uint4*)(d + e) = o;
}

__global__ __launch_bounds__(256) void tcvt_all(
    const float* __restrict__ gcnw, const float* __restrict__ f1w, const float* __restrict__ f2w,
    ushort* __restrict__ gw0, ushort* __restrict__ gw1,
    ushort* __restrict__ f1t, ushort* __restrict__ f2t)
{
    int by = blockIdx.y;
    const float* src; ushort* dst; int R, C;
    if (by < 16)       { src = gcnw;          dst = gw0; R = 512;  C = 512; }
    else if (by < 32)  { src = gcnw + 262144; dst = gw1; R = 512;  C = 512; by -= 16; }
    else if (by < 224) { src = f1w;           dst = f1t; R = 6144; C = 512; by -= 32; }
    else               { src = f2w;           dst = f2t; R = 512;  C = 512; by -= 224; }
    __shared__ float tl[32][33];
    const int c0 = blockIdx.x * 32, r0 = by * 32;
    const int cx = threadIdx.x & 31, ry = threadIdx.x >> 5;
    #pragma unroll
    for (int k = 0; k < 4; ++k) tl[ry + k * 8][cx] = src[(long)(r0 + ry + k * 8) * C + c0 + cx];
    __syncthreads();
    #pragma unroll
    for (int k = 0; k < 4; ++k) dst[(long)(c0 + ry + k * 8) * R + r0 + cx] = f2b(tl[cx][ry + k * 8]);
}

// =============== graph-learning: conv0+conv1+conv2+cheb in one dispatch ===============
// 1536 blocks each do 4 rows of y2; last block (atomic ticket) builds Chebyshev basis.
__global__ __launch_bounds__(256) void conv01_cheb(
    const ushort* __restrict__ G, const float* __restrict__ w0, const float* __restrict__ b0,
    const float* __restrict__ w1, const float* __restrict__ b1,
    const float* __restrict__ w2, const float* __restrict__ b2,
    float* __restrict__ y2, float* __restrict__ cheb, unsigned* __restrict__ done)
{
    const int tid = threadIdx.x;
    {
        const int row = (blockIdx.x * 256 + tid) >> 6;   // b*12+c
        const int lane = tid & 63;
        const int b = row / 12, c = row - 12 * b;
        const float w00 = w0[0], w01 = w0[1], w02 = w0[2], w03 = w0[3], bb = b0[0];
        const ushort* gp = G + ((long)(b * 4) * 12 + c) * 512;
        float s = 0.f;
        for (int f = lane; f < 512; f += 64) {
            const float v = bb + b2f(gp[f]) * w00 + b2f(gp[6144 + f]) * w01
                          + b2f(gp[12288 + f]) * w02 + b2f(gp[18432 + f]) * w03;
            s += fmaxf(v, 0.f) * w1[f];
        }
        #pragma unroll
        for (int off = 32; off; off >>= 1) s += __shfl_down(s, off);
        if (lane == 0) y2[row] = fmaxf(s + b1[0], 0.f);
    }
    __syncthreads();                                // drain stores to L2
    __shared__ unsigned ticket;
    if (tid == 0)
        ticket = __hip_atomic_fetch_add(done, 1u, __ATOMIC_ACQ_REL, __HIP_MEMORY_SCOPE_AGENT);
    __syncthreads();
    if (ticket != gridDim.x - 1) return;

    // last block: y2 fully visible (acquire). Build adjacency -> Laplacian -> Chebyshev.
    __shared__ float ys[6144];
    __shared__ float adj[144], deg[12], dhat[12], lap[144], T2[144];
    for (int i = tid; i < 6144; i += 256) ys[i] = y2[i];
    __syncthreads();
    if (tid < 144) {
        float wk[12];
        #pragma unroll
        for (int c = 0; c < 12; ++c) wk[c] = w2[tid * 12 + c];
        const float bias = b2[tid];
        float s = 0.f;
        for (int b = 0; b < 512; ++b) {
            float v = bias;
            #pragma unroll
            for (int c = 0; c < 12; ++c) v += ys[b * 12 + c] * wk[c];
            s += fmaxf(v, 0.f);
        }
        adj[tid] = fmaxf(s * (1.f / 512.f), 0.f);
    }
    __syncthreads();
    if (tid < 12) {
        float s = 0.f;
        for (int j = 0; j < 12; ++j) s += adj[tid * 12 + j];
        deg[tid] = s; dhat[tid] = 1.f / (sqrtf(s) + 1e-7f);
    }
    __syncthreads();
    if (tid < 144) {
        const int i = tid / 12, j = tid % 12;
        const float as = 0.5f * (adj[i * 12 + j] + adj[j * 12 + i]);
        lap[tid] = dhat[i] * ((i == j ? deg[i] : 0.f) - as) * dhat[j];
    }
    __syncthreads();
    if (tid < 144) {
        const int i = tid / 12, j = tid % 12;
        float s = 0.f;
        for (int kk = 0; kk < 12; ++kk) s += lap[i * 12 + kk] * lap[kk * 12 + j];
        T2[tid] = 2.f * s;
    }
    __syncthreads();
    if (tid < 144) {
        const int i = tid / 12, j = tid % 12;
        float s = 0.f;
        for (int kk = 0; kk < 12; ++kk) s += lap[i * 12 + kk] * T2[kk * 12 + j];
        cheb[tid] = 0.f;
        cheb[144 + tid] = lap[tid];
        cheb[288 + tid] = T2[tid];
        cheb[432 + tid] = 2.f * s - lap[tid];
    }
}

// =============== GCN epilogues ===============
__global__ __launch_bounds__(256) void gcn_epi1(
    const ushort* __restrict__ S, const float* __restrict__ cheb,
    const float* __restrict__ gcnb, const ushort* __restrict__ G,
    ushort* __restrict__ H1)
{
    __shared__ float ch[576];
    const int tid = threadIdx.x;
    for (int i = tid; i < 576; i += 256) ch[i] = cheb[i];
    __syncthreads();
    const int idx = blockIdx.x * 256 + tid;
    const int f = idx & 511, bc = idx >> 9;
    const int b = bc / 12, c = bc - 12 * b;
    const float bias = gcnb[f];
    #pragma unroll
    for (int w = 0; w < 4; ++w) {
        float o = bias;
        const ushort* Sr = S + ((b * 4 + w) * 12) * 512 + f;
        const float* cw = ch + w * 144 + c * 12;
        #pragma unroll
        for (int j = 0; j < 12; ++j) o += cw[j] * b2f(Sr[j * 512]);
        const int gi = ((b * 4 + w) * 12 + c) * 512 + f;
        H1[gi] = f2b(fmaxf(o, 0.f) + b2f(G[gi]));
    }
}

__global__ __launch_bounds__(256) void gcn_epi2(
    const ushort* __restrict__ S, const float* __restrict__ cheb,
    const float* __restrict__ gcnb, const ushort* __restrict__ G,
    const ushort* __restrict__ H1, ushort* __restrict__ pooled)
{
    __shared__ float ch[576];
    const int tid = threadIdx.x;
    for (int i = tid; i < 576; i += 256) ch[i] = cheb[i];
    __syncthreads();
    const int idx = blockIdx.x * 256 + tid;
    const int f = idx & 511, bc = idx >> 9;
    const int b = bc / 12, c = bc - 12 * b;
    const float bias = gcnb[f];
    float acc = 0.f;
    #pragma unroll
    for (int w = 0; w < 4; ++w) {
        float o = bias;
        const ushort* Sr = S + ((b * 4 + w) * 12) * 512 + f;
        const float* cw = ch + w * 144 + c * 12;
        #pragma unroll
        for (int j = 0; j < 12; ++j) o += cw[j] * b2f(Sr[j * 512]);
        const int gi = ((b * 4 + w) * 12 + c) * 512 + f;
        acc += fmaxf(o, 0.f) + b2f(H1[gi]) + b2f(G[gi]);
    }
    pooled[idx] = f2b(acc);
}

// =============== head epilogues ===============
__global__ __launch_bounds__(256) void fc_epi(
    const float* __restrict__ part, int nsplit, const float* __restrict__ bias,
    const float* __restrict__ g, const float* __restrict__ be,
    const float* __restrict__ mu, const float* __restrict__ var,
    ushort* __restrict__ outb, float* __restrict__ outf)
{
    const int idx = blockIdx.x * 256 + threadIdx.x;
    const int c = idx & 511;
    float s = bias[c];
    for (int k = 0; k < nsplit; ++k) s += part[k * 262144 + idx];
    s = s >= 0.f ? s : 0.01f * s;
    s = (s - mu[c]) * rsqrtf(var[c] + 1e-5f) * g[c] + be[c];
    if (outb) outb[idx] = f2b(s); else outf[idx] = s;
}

__global__ __launch_bounds__(256) void fc3_kernel(
    const float* __restrict__ z2, const float* __restrict__ w3,
    const float* __restrict__ b3, float* __restrict__ out)
{
    const int idx = blockIdx.x * 256 + threadIdx.x;
    const int m = idx >> 2, nc = idx & 3;
    float s = b3[nc];
    const float* zr = z2 + m * 512;
    for (int k = 0; k < 512; ++k) s += zr[k] * w3[k * 4 + nc];
    out[idx] = s;
}

extern "C" void kernel_launch(void* const* d_in, const int* in_sizes, int n_in,
                              void* d_out, int out_size, void* d_ws, size_t ws_size,
                              hipStream_t stream)
{
    (void)in_sizes; (void)n_in; (void)out_size; (void)ws_size;
    const float* x    = (const float*)d_in[0];
    const float* wih  = (const float*)d_in[1];
    const float* whh  = (const float*)d_in[2];
    const float* bih  = (const float*)d_in[3];
    const float* bhh  = (const float*)d_in[4];
    const float* c0w  = (const float*)d_in[5];
    const float* c0b  = (const float*)d_in[6];
    const float* c1w  = (const float*)d_in[7];
    const float* c1b  = (const float*)d_in[8];
    const float* c2w  = (const float*)d_in[9];
    const float* c2b  = (const float*)d_in[10];
    const float* gcnw = (const float*)d_in[11];
    const float* gcnb = (const float*)d_in[12];
    const float* f1w  = (const float*)d_in[13];
    const float* f1b  = (const float*)d_in[14];
    const float* bn1g = (const float*)d_in[15];
    const float* bn1b = (const float*)d_in[16];
    const float* bn1m = (const float*)d_in[17];
    const float* bn1v = (const float*)d_in[18];
    const float* f2w  = (const float*)d_in[19];
    const float* f2b_ = (const float*)d_in[20];
    const float* bn2g = (const float*)d_in[21];
    const float* bn2b = (const float*)d_in[22];
    const float* bn2m = (const float*)d_in[23];
    const float* bn2v = (const float*)d_in[24];
    const float* f3w  = (const float*)d_in[25];
    const float* f3b  = (const float*)d_in[26];

    // ---- workspace layout (bytes), aliased ----
    char* W = (char*)d_ws;
    ushort* xb     = (ushort*)(W + 0);             // 25.2 MB (dead after GRU)
    ushort* pooled = (ushort*)(W + 0);             //  6.3 MB (alias xb)
    float*  z1p    = (float*)(W + 8388608);        // 16.8 MB (alias xb tail)
    float*  z2p    = z1p;                          //  4.2 MB (alias)
    ushort* G      = (ushort*)(W + 25165824);      // 25.2 MB
    ushort* S      = (ushort*)(W + 50331648);      // 25.2 MB
    ushort* H1     = (ushort*)(W + 75497472);      // 25.2 MB
    ushort* h0     = (ushort*)(W + 100663296);     //  2.1 MB
    ushort* h1     = (ushort*)(W + 102760448);     //  2.1 MB
    ushort* wihB   = (ushort*)(W + 104857600);     //  1.6 MB
    ushort* whhB   = (ushort*)(W + 106430464);     //  1.6 MB
    ushort* gw0    = (ushort*)(W + 108003328);     //  0.5 MB
    ushort* gw1    = (ushort*)(W + 108527616);     //  0.5 MB
    ushort* f1t    = (ushort*)(W + 109051904);     //  6.3 MB
    ushort* f2t    = (ushort*)(W + 115343360);     //  0.5 MB
    ushort* z1b    = (ushort*)(W + 115867648);     //  0.5 MB
    float*  z2     = (float*)(W + 116391936);      //  1.0 MB
    float*  y2     = (float*)(W + 117440512);      //  24.6 KB
    float*  chebb  = (float*)(W + 117465088);      //  2.3 KB
    unsigned* sync = (unsigned*)(W + 117469184);   //  64 B: cnt[12] + done

    // ---- prep ----
    hipMemsetAsync(h0, 0, (size_t)Nn * Ff * sizeof(ushort), stream);
    hipMemsetAsync(sync, 0, 64, stream);
    cvt_x<<<(Mx * 64) / 256, 256, 0, stream>>>(x, xb);
    cvt_w2<<<768, 256, 0, stream>>>(wih, whh, wihB, whhB);
    tcvt_all<<<dim3(16, 240), 256, 0, stream>>>(gcnw, f1w, f2w, gw0, gw1, f1t, f2t);

    // ---- GRU: 12 steps in ONE dispatch ----
    gru_all<<<512, 256, 0, stream>>>(xb, whhB, wihB, bih, bhh, h0, h1, G, sync);

    // ---- graph learning (1 dispatch) ----
    conv01_cheb<<<(Bb * Cc * 64) / 256, 256, 0, stream>>>(
        G, c0w, c0b, c1w, c1b, c2w, c2b, y2, chebb, sync + 12);

    // ---- GCN layer 1 ----
    mfma_gemm<<<dim3(768, 1), 256, 0, stream>>>(
        G, gw0, nullptr, S, nullptr, Ff, Ff, Ff, 0, 192);
    gcn_epi1<<<(Bb * Cc * Ff) / 256, 256, 0, stream>>>(S, chebb, gcnb, G, H1);

    // ---- GCN layer 2 + pool ----
    mfma_gemm<<<dim3(768, 1), 256, 0, stream>>>(
        H1, gw1, nullptr, S, nullptr, Ff, Ff, Ff, 0, 192);
    gcn_epi2<<<(Bb * Cc * Ff) / 256, 256, 0, stream>>>(S, chebb, gcnb + Ff, G, H1, pooled);

    // ---- head ----
    mfma_gemm<<<dim3(16, 16), 256, 0, stream>>>(
        pooled, f1t, z1p, nullptr, nullptr, 512, Cc * Ff, 384, 262144, 4);
    fc_epi<<<1024, 256, 0, stream>>>(z1p, 16, f1b, bn1g, bn1b, bn1m, bn1v, z1b, nullptr);
    mfma_gemm<<<dim3(16, 4), 256, 0, stream>>>(
        z1b, f2t, z2p, nullptr, nullptr, 512, 512, 128, 262144, 4);
    fc_epi<<<1024, 256, 0, stream>>>(z2p, 4, f2b_, bn2g, bn2b, bn2m, bn2v, nullptr, z2);
    fc3_kernel<<<(Bb * 4) / 256, 256, 0, stream>>>(z2, f3w, f3b, (float*)d_out);
}

// Round 9
// 579.917 us; speedup vs baseline: 1.7708x; 1.7708x over previous
//
#include <hip/hip_runtime.h>
#include <cmath>

// ---- problem constants ----
constexpr int Bb  = 512;
constexpr int Cc  = 12;
constexpr int Ww  = 4;
constexpr int Ff  = 512;
constexpr int Nn  = Bb * Ww;        // 2048
constexpr int Gg  = 3 * Ff;         // 1536
constexpr int Mx  = Nn * Cc;        // 24576

typedef __attribute__((ext_vector_type(8))) short bf16x8;
typedef __attribute__((ext_vector_type(4))) float f32x4;

__device__ __forceinline__ float sigm(float v) { return 1.f / (1.f + expf(-v)); }
__device__ __forceinline__ float b2f(ushort u) { union { float f; unsigned i; } v; v.i = ((unsigned)u) << 16; return v.f; }
__device__ __forceinline__ ushort f2b(float f) {
    union { float f; unsigned i; } v; v.f = f;
    unsigned r = v.i + 0x7FFFu + ((v.i >> 16) & 1u);
    return (ushort)(r >> 16);
}
__device__ __forceinline__ void async16(const ushort* g, ushort* l) {
    __builtin_amdgcn_global_load_lds(
        (const __attribute__((address_space(1))) unsigned int*)g,
        (__attribute__((address_space(3))) unsigned int*)l, 16, 0, 0);
}

// =============== generic bf16 MFMA GEMM (R4-verbatim) ===============
__global__ __launch_bounds__(256) void mfma_gemm(
    const ushort* __restrict__ A, const ushort* __restrict__ Bt,
    float* __restrict__ Cf, ushort* __restrict__ Cb,
    int N, int K, int kLen, int MN, int gridY)
{
    __shared__ ushort As[128 * 64], Bs[128 * 64];
    const int tid = threadIdx.x;
    const int ln = tid & 63, wv = tid >> 6;
    const int l = blockIdx.x;
    const int by = l % gridY, bx = l / gridY, bz = blockIdx.y;
    const int srow = ln >> 3;
    const int kslot = (ln & 7) ^ srow;
    const ushort* ga = A  + (long)(by * 128 + wv * 32 + srow) * K + bz * kLen + kslot * 8;
    const ushort* gb = Bt + (long)(bx * 128 + wv * 32 + srow) * K + bz * kLen + kslot * 8;
    ushort* la = As + wv * 32 * 64;
    ushort* lb = Bs + wv * 32 * 64;
    const int rbase = (wv >> 1) * 64, cbase = (wv & 1) * 64;
    const int mrow = ln & 15, quad = ln >> 4;

    f32x4 acc[4][4] = {};

    for (int kc = 0; kc < kLen; kc += 64) {
        #pragma unroll
        for (int i = 0; i < 4; ++i) {
            async16(ga + (long)(i * 8) * K, la + i * 8 * 64);
            async16(gb + (long)(i * 8) * K, lb + i * 8 * 64);
        }
        ga += 64; gb += 64;
        __syncthreads();
        #pragma unroll
        for (int s = 0; s < 2; ++s) {
            const int sw = (((s << 2) + quad) ^ (ln & 7)) << 3;
            bf16x8 af[4], bf[4];
            #pragma unroll
            for (int i = 0; i < 4; ++i)
                af[i] = *(const bf16x8*)(As + (rbase + i * 16 + mrow) * 64 + sw);
            #pragma unroll
            for (int j = 0; j < 4; ++j)
                bf[j] = *(const bf16x8*)(Bs + (cbase + j * 16 + mrow) * 64 + sw);
            #pragma unroll
            for (int i = 0; i < 4; ++i)
                #pragma unroll
                for (int j = 0; j < 4; ++j)
                    acc[i][j] = __builtin_amdgcn_mfma_f32_16x16x32_bf16(bf[j], af[i], acc[i][j], 0, 0, 0);
        }
        __syncthreads();
    }

    const int gr0 = by * 128 + rbase + mrow;
    const int gc0 = bx * 128 + cbase + quad * 4;
    if (Cb) {
        #pragma unroll
        for (int i = 0; i < 4; ++i) {
            const long rowoff = (long)(gr0 + i * 16) * N;
            #pragma unroll
            for (int j = 0; j < 4; ++j) {
                union { ushort u[4]; uint2 v; } pk;
                pk.u[0] = f2b(acc[i][j][0]); pk.u[1] = f2b(acc[i][j][1]);
                pk.u[2] = f2b(acc[i][j][2]); pk.u[3] = f2b(acc[i][j][3]);
                *(uint2*)&Cb[rowoff + gc0 + j * 16] = pk.v;
            }
        }
    } else {
        float* Co = Cf + (long)bz * MN;
        #pragma unroll
        for (int i = 0; i < 4; ++i) {
            const long rowoff = (long)(gr0 + i * 16) * N;
            #pragma unroll
            for (int j = 0; j < 4; ++j)
                *(f32x4*)&Co[rowoff + gc0 + j * 16] = acc[i][j];
        }
    }
}

// =============== fused GRU step (dual GEMM; t==0 skips h path — exact zeros) ===============
__global__ __launch_bounds__(256) void gru_fused(
    const ushort* __restrict__ hin, const ushort* __restrict__ xb,
    const ushort* __restrict__ whhB, const ushort* __restrict__ wihB,
    const float* __restrict__ bih, const float* __restrict__ bhh,
    ushort* __restrict__ hout, ushort* __restrict__ G, int t)
{
    __shared__ ushort Ah[64 * 64], Ax[64 * 64], Bh[96 * 64], Bx[96 * 64];
    const int tid = threadIdx.x, ln = tid & 63, wv = tid >> 6;
    const int p = blockIdx.x;
    const int fb = ((p & 7) << 1) | (p >> 8);   // XCD-pin weight f-slices
    const int mb = (p >> 3) & 31;
    const int srow = ln >> 3, kslot = (ln & 7) ^ srow;
    const int mrow = ln & 15, quad = ln >> 4;
    const int th = (t != 0);
    f32x4 aH[6] = {}, aX[6] = {};
    const ushort* hrow = hin + (long)(mb * 64) * 512;

    for (int kc = 0; kc < 512; kc += 64) {
        #pragma unroll
        for (int a = 0; a < 2; ++a) {
            const int r0 = (wv * 2 + a) * 8;
            if (th) async16(hrow + (long)(r0 + srow) * 512 + kc + kslot * 8, Ah + r0 * 64);
            async16(xb + ((long)(mb * 64 + r0 + srow) * 12 + t) * 512 + kc + kslot * 8, Ax + r0 * 64);
        }
        #pragma unroll
        for (int b8 = 0; b8 < 3; ++b8) {
            const int lr0 = (wv * 3 + b8) * 8;
            const int lr = lr0 + srow;
            const int g = lr >> 5, fc = lr & 31;
            const long wr = (long)(g * 512 + fb * 32 + fc) * 512 + kc + kslot * 8;
            if (th) async16(whhB + wr, Bh + lr0 * 64);
            async16(wihB + wr, Bx + lr0 * 64);
        }
        __syncthreads();
        #pragma unroll
        for (int s = 0; s < 2; ++s) {
            const int sw = (((s << 2) + quad) ^ (ln & 7)) << 3;
            const bf16x8 ax = *(const bf16x8*)(Ax + (wv * 16 + mrow) * 64 + sw);
            #pragma unroll
            for (int jt = 0; jt < 6; ++jt) {
                const bf16x8 bx2 = *(const bf16x8*)(Bx + (jt * 16 + mrow) * 64 + sw);
                aX[jt] = __builtin_amdgcn_mfma_f32_16x16x32_bf16(bx2, ax, aX[jt], 0, 0, 0);
            }
            if (th) {
                const bf16x8 ah = *(const bf16x8*)(Ah + (wv * 16 + mrow) * 64 + sw);
                #pragma unroll
                for (int jt = 0; jt < 6; ++jt) {
                    const bf16x8 bh = *(const bf16x8*)(Bh + (jt * 16 + mrow) * 64 + sw);
                    aH[jt] = __builtin_amdgcn_mfma_f32_16x16x32_bf16(bh, ah, aH[jt], 0, 0, 0);
                }
            }
        }
        __syncthreads();
    }

    const int n = mb * 64 + wv * 16 + mrow;
    #pragma unroll
    for (int ft = 0; ft < 2; ++ft) {
        const int f0 = fb * 32 + ft * 16 + quad * 4;
        const float4 bir = *(const float4*)(bih + f0);
        const float4 biz = *(const float4*)(bih + 512 + f0);
        const float4 bin = *(const float4*)(bih + 1024 + f0);
        const float4 bhr = *(const float4*)(bhh + f0);
        const float4 bhz = *(const float4*)(bhh + 512 + f0);
        const float4 bhn = *(const float4*)(bhh + 1024 + f0);
        const float br[4] = {bir.x + bhr.x, bir.y + bhr.y, bir.z + bhr.z, bir.w + bhr.w};
        const float bz[4] = {biz.x + bhz.x, biz.y + bhz.y, biz.z + bhz.z, biz.w + bhz.w};
        const float bnI[4] = {bin.x, bin.y, bin.z, bin.w};
        const float bnH[4] = {bhn.x, bhn.y, bhn.z, bhn.w};
        union { ushort u[4]; uint2 v; } hpk;
        if (th) hpk.v = *(const uint2*)(hin + (long)n * 512 + f0);
        union { ushort u[4]; uint2 v; } o;
        #pragma unroll
        for (int r = 0; r < 4; ++r) {
            const float hprev = th ? b2f(hpk.u[r]) : 0.f;
            const float rr = sigm(aH[ft][r] + aX[ft][r] + br[r]);
            const float zz = sigm(aH[2 + ft][r] + aX[2 + ft][r] + bz[r]);
            const float nv = tanhf(aX[4 + ft][r] + bnI[r] + rr * (aH[4 + ft][r] + bnH[r]));
            o.u[r] = f2b((1.f - zz) * nv + zz * hprev);
        }
        *(uint2*)&hout[(long)n * 512 + f0] = o.v;
        *(uint2*)&G[(long)(n * 12 + t) * 512 + f0] = o.v;
    }
}

// =============== prep: all conversions + sync zero, one dispatch ===============
__global__ __launch_bounds__(256) void prep_all(
    const float* __restrict__ x, ushort* __restrict__ xb,
    const float* __restrict__ wih, const float* __restrict__ whh,
    ushort* __restrict__ wihB, ushort* __restrict__ whhB,
    const float* __restrict__ gcnw, const float* __restrict__ f1w, const float* __restrict__ f2w,
    ushort* __restrict__ gw0, ushort* __restrict__ gw1,
    ushort* __restrict__ f1t, ushort* __restrict__ f2t,
    unsigned* __restrict__ sync)
{
    __shared__ float tl[32][33];
    const int bx = blockIdx.x, tid = threadIdx.x;
    if (bx == 0 && tid < 16) sync[tid] = 0;
    if (bx < 6144) {                       // cvt_x
        const int idx = bx * 256 + tid;
        const int m = idx >> 6, f8 = (idx & 63) << 3;
        const int n = m / 12, c = m - n * 12;
        const int b = n >> 2, w = n & 3;
        const float* src = x + (((b * 12 + c) * 4 + w) << 9) + f8;
        const float4 a = *(const float4*)src, q = *(const float4*)(src + 4);
        uint4 o;
        o.x = (unsigned)f2b(a.x) | ((unsigned)f2b(a.y) << 16);
        o.y = (unsigned)f2b(a.z) | ((unsigned)f2b(a.w) << 16);
        o.z = (unsigned)f2b(q.x) | ((unsigned)f2b(q.y) << 16);
        o.w = (unsigned)f2b(q.z) | ((unsigned)f2b(q.w) << 16);
        *(uint4*)(xb + (m << 9) + f8) = o;
    } else if (bx < 6912) {                // cvt wih/whh
        int b2 = bx - 6144;
        const float* s; ushort* d;
        if (b2 < 384) { s = wih; d = wihB; } else { s = whh; d = whhB; b2 -= 384; }
        const int e = (b2 * 256 + tid) << 3;
        const float4 a = *(const float4*)(s + e), q = *(const float4*)(s + e + 4);
        uint4 o;
        o.x = (unsigned)f2b(a.x) | ((unsigned)f2b(a.y) << 16);
        o.y = (unsigned)f2b(a.z) | ((unsigned)f2b(a.w) << 16);
        o.z = (unsigned)f2b(q.x) | ((unsigned)f2b(q.y) << 16);
        o.w = (unsigned)f2b(q.z) | ((unsigned)f2b(q.w) << 16);
        *(uint4*)(d + e) = o;
    } else {                               // transpose-converts
        int idx = bx - 6912;               // 0..3839
        const int tx = idx & 15;
        int by = idx >> 4;                 // 0..239
        const float* src; ushort* dst; int R, C;
        if (by < 16)       { src = gcnw;          dst = gw0; R = 512;  C = 512; }
        else if (by < 32)  { src = gcnw + 262144; dst = gw1; R = 512;  C = 512; by -= 16; }
        else if (by < 224) { src = f1w;           dst = f1t; R = 6144; C = 512; by -= 32; }
        else               { src = f2w;           dst = f2t; R = 512;  C = 512; by -= 224; }
        const int c0 = tx * 32, r0 = by * 32;
        const int cx = tid & 31, ry = tid >> 5;
        #pragma unroll
        for (int k = 0; k < 4; ++k) tl[ry + k * 8][cx] = src[(long)(r0 + ry + k * 8) * C + c0 + cx];
        __syncthreads();
        #pragma unroll
        for (int k = 0; k < 4; ++k) dst[(long)(c0 + ry + k * 8) * R + r0 + cx] = f2b(tl[cx][ry + k * 8]);
    }
}

// =============== graph-learning: conv0+conv1+conv2+cheb, one dispatch ===============
__global__ __launch_bounds__(256) void conv01_cheb(
    const ushort* __restrict__ G, const float* __restrict__ w0, const float* __restrict__ b0,
    const float* __restrict__ w1, const float* __restrict__ b1,
    const float* __restrict__ w2, const float* __restrict__ b2,
    float* __restrict__ y2, float* __restrict__ cheb, unsigned* __restrict__ done)
{
    const int tid = threadIdx.x;
    {
        const int row = (blockIdx.x * 256 + tid) >> 6;
        const int lane = tid & 63;
        const int b = row / 12, c = row - 12 * b;
        const float w00 = w0[0], w01 = w0[1], w02 = w0[2], w03 = w0[3], bb = b0[0];
        const ushort* gp = G + ((long)(b * 4) * 12 + c) * 512;
        float s = 0.f;
        for (int f = lane; f < 512; f += 64) {
            const float v = bb + b2f(gp[f]) * w00 + b2f(gp[6144 + f]) * w01
                          + b2f(gp[12288 + f]) * w02 + b2f(gp[18432 + f]) * w03;
            s += fmaxf(v, 0.f) * w1[f];
        }
        #pragma unroll
        for (int off = 32; off; off >>= 1) s += __shfl_down(s, off);
        if (lane == 0) y2[row] = fmaxf(s + b1[0], 0.f);
    }
    __syncthreads();
    __shared__ unsigned ticket;
    if (tid == 0)
        ticket = __hip_atomic_fetch_add(done, 1u, __ATOMIC_ACQ_REL, __HIP_MEMORY_SCOPE_AGENT);
    __syncthreads();
    if (ticket != gridDim.x - 1) return;

    __shared__ float ys[6144];
    __shared__ float adj[144], deg[12], dhat[12], lap[144], T2[144];
    for (int i = tid; i < 6144; i += 256) ys[i] = y2[i];
    __syncthreads();
    if (tid < 144) {
        float wk[12];
        #pragma unroll
        for (int c = 0; c < 12; ++c) wk[c] = w2[tid * 12 + c];
        const float bias = b2[tid];
        float s = 0.f;
        for (int b = 0; b < 512; ++b) {
            float v = bias;
            #pragma unroll
            for (int c = 0; c < 12; ++c) v += ys[b * 12 + c] * wk[c];
            s += fmaxf(v, 0.f);
        }
        adj[tid] = fmaxf(s * (1.f / 512.f), 0.f);
    }
    __syncthreads();
    if (tid < 12) {
        float s = 0.f;
        for (int j = 0; j < 12; ++j) s += adj[tid * 12 + j];
        deg[tid] = s; dhat[tid] = 1.f / (sqrtf(s) + 1e-7f);
    }
    __syncthreads();
    if (tid < 144) {
        const int i = tid / 12, j = tid % 12;
        const float as = 0.5f * (adj[i * 12 + j] + adj[j * 12 + i]);
        lap[tid] = dhat[i] * ((i == j ? deg[i] : 0.f) - as) * dhat[j];
    }
    __syncthreads();
    if (tid < 144) {
        const int i = tid / 12, j = tid % 12;
        float s = 0.f;
        for (int kk = 0; kk < 12; ++kk) s += lap[i * 12 + kk] * lap[kk * 12 + j];
        T2[tid] = 2.f * s;
    }
    __syncthreads();
    if (tid < 144) {
        const int i = tid / 12, j = tid % 12;
        float s = 0.f;
        for (int kk = 0; kk < 12; ++kk) s += lap[i * 12 + kk] * T2[kk * 12 + j];
        cheb[tid] = 0.f;
        cheb[144 + tid] = lap[tid];
        cheb[288 + tid] = T2[tid];
        cheb[432 + tid] = 2.f * s - lap[tid];
    }
}

// =============== GCN epilogues (R4-verbatim) ===============
__global__ __launch_bounds__(256) void gcn_epi1(
    const ushort* __restrict__ S, const float* __restrict__ cheb,
    const float* __restrict__ gcnb, const ushort* __restrict__ G,
    ushort* __restrict__ H1)
{
    __shared__ float ch[576];
    const int tid = threadIdx.x;
    for (int i = tid; i < 576; i += 256) ch[i] = cheb[i];
    __syncthreads();
    const int idx = blockIdx.x * 256 + tid;
    const int f = idx & 511, bc = idx >> 9;
    const int b = bc / 12, c = bc - 12 * b;
    const float bias = gcnb[f];
    #pragma unroll
    for (int w = 0; w < 4; ++w) {
        float o = bias;
        const ushort* Sr = S + ((b * 4 + w) * 12) * 512 + f;
        const float* cw = ch + w * 144 + c * 12;
        #pragma unroll
        for (int j = 0; j < 12; ++j) o += cw[j] * b2f(Sr[j * 512]);
        const int gi = ((b * 4 + w) * 12 + c) * 512 + f;
        H1[gi] = f2b(fmaxf(o, 0.f) + b2f(G[gi]));
    }
}

__global__ __launch_bounds__(256) void gcn_epi2(
    const ushort* __restrict__ S, const float* __restrict__ cheb,
    const float* __restrict__ gcnb, const ushort* __restrict__ G,
    const ushort* __restrict__ H1, ushort* __restrict__ pooled)
{
    __shared__ float ch[576];
    const int tid = threadIdx.x;
    for (int i = tid; i < 576; i += 256) ch[i] = cheb[i];
    __syncthreads();
    const int idx = blockIdx.x * 256 + tid;
    const int f = idx & 511, bc = idx >> 9;
    const int b = bc / 12, c = bc - 12 * b;
    const float bias = gcnb[f];
    float acc = 0.f;
    #pragma unroll
    for (int w = 0; w < 4; ++w) {
        float o = bias;
        const ushort* Sr = S + ((b * 4 + w) * 12) * 512 + f;
        const float* cw = ch + w * 144 + c * 12;
        #pragma unroll
        for (int j = 0; j < 12; ++j) o += cw[j] * b2f(Sr[j * 512]);
        const int gi = ((b * 4 + w) * 12 + c) * 512 + f;
        acc += fmaxf(o, 0.f) + b2f(H1[gi]) + b2f(G[gi]);
    }
    pooled[idx] = f2b(acc);
}

// =============== head epilogues (R4-verbatim) ===============
__global__ __launch_bounds__(256) void fc_epi(
    const float* __restrict__ part, int nsplit, const float* __restrict__ bias,
    const float* __restrict__ g, const float* __restrict__ be,
    const float* __restrict__ mu, const float* __restrict__ var,
    ushort* __restrict__ outb, float* __restrict__ outf)
{
    const int idx = blockIdx.x * 256 + threadIdx.x;
    const int c = idx & 511;
    float s = bias[c];
    for (int k = 0; k < nsplit; ++k) s += part[k * 262144 + idx];
    s = s >= 0.f ? s : 0.01f * s;
    s = (s - mu[c]) * rsqrtf(var[c] + 1e-5f) * g[c] + be[c];
    if (outb) outb[idx] = f2b(s); else outf[idx] = s;
}

__global__ __launch_bounds__(256) void fc3_kernel(
    const float* __restrict__ z2, const float* __restrict__ w3,
    const float* __restrict__ b3, float* __restrict__ out)
{
    const int idx = blockIdx.x * 256 + threadIdx.x;
    const int m = idx >> 2, nc = idx & 3;
    float s = b3[nc];
    const float* zr = z2 + m * 512;
    for (int k = 0; k < 512; ++k) s += zr[k] * w3[k * 4 + nc];
    out[idx] = s;
}

extern "C" void kernel_launch(void* const* d_in, const int* in_sizes, int n_in,
                              void* d_out, int out_size, void* d_ws, size_t ws_size,
                              hipStream_t stream)
{
    (void)in_sizes; (void)n_in; (void)out_size; (void)ws_size;
    const float* x    = (const float*)d_in[0];
    const float* wih  = (const float*)d_in[1];
    const float* whh  = (const float*)d_in[2];
    const float* bih  = (const float*)d_in[3];
    const float* bhh  = (const float*)d_in[4];
    const float* c0w  = (const float*)d_in[5];
    const float* c0b  = (const float*)d_in[6];
    const float* c1w  = (const float*)d_in[7];
    const float* c1b  = (const float*)d_in[8];
    const float* c2w  = (const float*)d_in[9];
    const float* c2b  = (const float*)d_in[10];
    const float* gcnw = (const float*)d_in[11];
    const float* gcnb = (const float*)d_in[12];
    const float* f1w  = (const float*)d_in[13];
    const float* f1b  = (const float*)d_in[14];
    const float* bn1g = (const float*)d_in[15];
    const float* bn1b = (const float*)d_in[16];
    const float* bn1m = (const float*)d_in[17];
    const float* bn1v = (const float*)d_in[18];
    const float* f2w  = (const float*)d_in[19];
    const float* f2b_ = (const float*)d_in[20];
    const float* bn2g = (const float*)d_in[21];
    const float* bn2b = (const float*)d_in[22];
    const float* bn2m = (const float*)d_in[23];
    const float* bn2v = (const float*)d_in[24];
    const float* f3w  = (const float*)d_in[25];
    const float* f3b  = (const float*)d_in[26];

    // ---- workspace layout (bytes), aliased (R4 layout) ----
    char* W = (char*)d_ws;
    ushort* xb     = (ushort*)(W + 0);             // 25.2 MB (dead after GRU)
    ushort* pooled = (ushort*)(W + 0);             //  6.3 MB (alias xb)
    float*  z1p    = (float*)(W + 8388608);        // 16.8 MB (alias xb tail)
    float*  z2p    = z1p;                          //  4.2 MB (alias)
    ushort* G      = (ushort*)(W + 25165824);      // 25.2 MB
    ushort* S      = (ushort*)(W + 50331648);      // 25.2 MB
    ushort* H1     = (ushort*)(W + 75497472);      // 25.2 MB
    ushort* h0     = (ushort*)(W + 100663296);     //  2.1 MB (never read: t=0 spec)
    ushort* h1     = (ushort*)(W + 102760448);     //  2.1 MB
    ushort* wihB   = (ushort*)(W + 104857600);     //  1.6 MB
    ushort* whhB   = (ushort*)(W + 106430464);     //  1.6 MB
    ushort* gw0    = (ushort*)(W + 108003328);     //  0.5 MB
    ushort* gw1    = (ushort*)(W + 108527616);     //  0.5 MB
    ushort* f1t    = (ushort*)(W + 109051904);     //  6.3 MB
    ushort* f2t    = (ushort*)(W + 115343360);     //  0.5 MB
    ushort* z1b    = (ushort*)(W + 115867648);     //  0.5 MB
    float*  z2     = (float*)(W + 116391936);      //  1.0 MB
    float*  y2     = (float*)(W + 117440512);      //  24.6 KB
    float*  chebb  = (float*)(W + 117465088);      //  2.3 KB
    unsigned* sync = (unsigned*)(W + 117469184);   //  64 B

    // ---- prep (one dispatch: conversions + sync zero) ----
    prep_all<<<10752, 256, 0, stream>>>(x, xb, wih, whh, wihB, whhB,
                                        gcnw, f1w, f2w, gw0, gw1, f1t, f2t, sync);

    // ---- GRU: 12 fused dual-GEMM steps, h ping-pong; t=0 skips h path ----
    ushort* hp = h0; ushort* hq = h1;
    for (int t = 0; t < Cc; ++t) {
        gru_fused<<<512, 256, 0, stream>>>(hp, xb, whhB, wihB, bih, bhh, hq, G, t);
        ushort* tmp = hp; hp = hq; hq = tmp;
    }

    // ---- graph learning (1 dispatch) ----
    conv01_cheb<<<(Bb * Cc * 64) / 256, 256, 0, stream>>>(
        G, c0w, c0b, c1w, c1b, c2w, c2b, y2, chebb, sync + 12);

    // ---- GCN layer 1 (R4-exact: GEMM -> S, then epilogue) ----
    mfma_gemm<<<dim3(768, 1), 256, 0, stream>>>(
        G, gw0, nullptr, S, Ff, Ff, Ff, 0, 192);
    gcn_epi1<<<(Bb * Cc * Ff) / 256, 256, 0, stream>>>(S, chebb, gcnb, G, H1);

    // ---- GCN layer 2 + pool ----
    mfma_gemm<<<dim3(768, 1), 256, 0, stream>>>(
        H1, gw1, nullptr, S, Ff, Ff, Ff, 0, 192);
    gcn_epi2<<<(Bb * Cc * Ff) / 256, 256, 0, stream>>>(S, chebb, gcnb + Ff, G, H1, pooled);

    // ---- head (R4-exact) ----
    mfma_gemm<<<dim3(16, 16), 256, 0, stream>>>(
        pooled, f1t, z1p, nullptr, 512, Cc * Ff, 384, 262144, 4);
    fc_epi<<<1024, 256, 0, stream>>>(z1p, 16, f1b, bn1g, bn1b, bn1m, bn1v, z1b, nullptr);
    mfma_gemm<<<dim3(16, 4), 256, 0, stream>>>(
        z1b, f2t, z2p, nullptr, 512, 512, 128, 262144, 4);
    fc_epi<<<1024, 256, 0, stream>>>(z2p, 4, f2b_, bn2g, bn2b, bn2m, bn2v, nullptr, z2);
    fc3_kernel<<<(Bb * 4) / 256, 256, 0, stream>>>(z2, f3w, f3b, (float*)d_out);
}